// Round 6
// baseline (261.231 us; speedup 1.0000x reference)
//
#include <hip/hip_runtime.h>
#include <math.h>

#define H 2048
#define V 50257
#define ML 25

// kDE geometry: persistent, co-resident
#define NBLK_DE 786
#define NW_DE   (NBLK_DE * 4)      // 3144 waves
#define NGRP    ((V + 3) / 4)      // 12565 groups of 4 rows

// ws layout: ints at [0..3], floats after
// wsi[0] = arrival counter, wsi[1] = flag, wsi[2] = LSE bits
#define WS_EMB 16                  // embedded [H]
#define WS_ATT (WS_EMB + H)        // attn_applied [H] (contiguous -> cat[2H])
#define WS_X   (WS_EMB + 2 * H)    // relu(combine) [H]
#define WS_GH  (WS_X + H)          // gh = W_hh@h + b_hh [3H]
#define WS_PM  (WS_GH + 3 * H)     // per-block max partials [NBLK_DE]
#define WS_PS  (WS_PM + 1024)      // per-block sumexp partials [NBLK_DE]

typedef float f4v __attribute__((ext_vector_type(4)));

__device__ __forceinline__ f4v ntload(const f4v* p) { return __builtin_nontemporal_load(p); }
__device__ __forceinline__ float dot4(f4v a, f4v b) {
    return a[0] * b[0] + a[1] * b[1] + a[2] * b[2] + a[3] * b[3];
}
__device__ __forceinline__ float wave_sum(float x) {
    #pragma unroll
    for (int off = 32; off; off >>= 1) x += __shfl_xor(x, off);
    return x;
}

// ============ kA: block 0 = embedding+attention; blocks 1..384 = gh = W_hh@h + b_hh ============
__global__ __launch_bounds__(1024)
void kA(const int* __restrict__ tok_p, const float* __restrict__ hidden,
        const float* __restrict__ enc_outs, const float* __restrict__ emb,
        const float* __restrict__ W_attn, const float* __restrict__ b_attn,
        const float* __restrict__ W_hh, const float* __restrict__ b_hh,
        float* __restrict__ ws, float* __restrict__ attnw)
{
    const int tid = threadIdx.x, bid = blockIdx.x;
    const int wv = tid >> 6, lane = tid & 63;

    if (bid == 0) {
        if (tid == 0) {   // reset kDE sync state every call (replay-safe)
            ((int*)ws)[0] = 0;
            ((int*)ws)[1] = 0;
        }
        __shared__ __align__(16) float s_cat[2 * H];
        __shared__ float s_aw[ML];
        const int tok = tok_p[0];   // int64 input, low word (LE)
        const float* erow = emb + (size_t)tok * H;
        for (int h = tid; h < H; h += 1024) {
            float e = erow[h];
            s_cat[h] = e; ws[WS_EMB + h] = e;
            s_cat[H + h] = hidden[h];
        }
        __syncthreads();
        const f4v* c4 = reinterpret_cast<const f4v*>(s_cat);
        for (int l = wv; l < ML; l += 16) {
            const f4v* w4 = reinterpret_cast<const f4v*>(W_attn + (size_t)l * (2 * H));
            float acc = 0.f;
            #pragma unroll
            for (int t = 0; t < 16; ++t) {
                int idx = t * 64 + lane;
                acc += dot4(w4[idx], c4[idx]);
            }
            acc = wave_sum(acc);
            if (lane == 0) s_aw[l] = acc + b_attn[l];
        }
        __syncthreads();
        if (tid == 0) {
            float m = s_aw[0];
            for (int l = 1; l < ML; ++l) m = fmaxf(m, s_aw[l]);
            float s = 0.f;
            for (int l = 0; l < ML; ++l) { float e = expf(s_aw[l] - m); s_aw[l] = e; s += e; }
            float inv = 1.f / s;
            for (int l = 0; l < ML; ++l) { float w = s_aw[l] * inv; s_aw[l] = w; attnw[l] = w; }
        }
        __syncthreads();
        for (int h = tid; h < H; h += 1024) {
            float acc = 0.f;
            #pragma unroll
            for (int l = 0; l < ML; ++l) acc += s_aw[l] * enc_outs[(size_t)l * H + h];
            ws[WS_ATT + h] = acc;
        }
    } else {
        const int r = (bid - 1) * 16 + wv;   // 6144 rows over 384 blocks
        if (r < 3 * H) {
            const f4v* w4 = reinterpret_cast<const f4v*>(W_hh + (size_t)r * H);
            const f4v* h4 = reinterpret_cast<const f4v*>(hidden);
            float acc = 0.f;
            #pragma unroll
            for (int t = 0; t < 8; ++t) {
                int idx = t * 64 + lane;
                acc += dot4(ntload(&w4[idx]), h4[idx]);
            }
            acc = wave_sum(acc);
            if (lane == 0) ws[WS_GH + r] = acc + b_hh[r];
        }
    }
}

// ============ kB: x = relu(W_comb @ cat + b_comb) ============
__global__ __launch_bounds__(256)
void kB(const float* __restrict__ W_comb, const float* __restrict__ b_comb,
        float* __restrict__ ws)
{
    const int tid = threadIdx.x;
    const int wv = tid >> 6, lane = tid & 63;
    const int k = blockIdx.x * 4 + wv;
    const f4v* w4 = reinterpret_cast<const f4v*>(W_comb + (size_t)k * (2 * H));
    const f4v* c4 = reinterpret_cast<const f4v*>(ws + WS_EMB);
    float acc = 0.f;
    #pragma unroll
    for (int t = 0; t < 16; ++t) {
        int idx = t * 64 + lane;
        acc += dot4(ntload(&w4[idx]), c4[idx]);
    }
    acc = wave_sum(acc);
    if (lane == 0) ws[WS_X + k] = fmaxf(acc + b_comb[k], 0.f);
}

// ============ kC: gi = W_ih @ x; gates; h_new ============
__global__ __launch_bounds__(256)
void kC(const float* __restrict__ W_ih, const float* __restrict__ b_ih,
        const float* __restrict__ hidden, const float* __restrict__ ws,
        float* __restrict__ h_out)
{
    const int tid = threadIdx.x;
    const int wv = tid >> 6, lane = tid & 63;
    const int k = blockIdx.x * 4 + wv;
    const f4v* x4 = reinterpret_cast<const f4v*>(ws + WS_X);
    const f4v* wr = reinterpret_cast<const f4v*>(W_ih + (size_t)k * H);
    const f4v* wz = reinterpret_cast<const f4v*>(W_ih + (size_t)(k + H) * H);
    const f4v* wn = reinterpret_cast<const f4v*>(W_ih + (size_t)(k + 2 * H) * H);
    float ar = 0.f, az = 0.f, an = 0.f;
    #pragma unroll
    for (int t = 0; t < 8; ++t) {
        int idx = t * 64 + lane;
        f4v xv = x4[idx];
        ar += dot4(ntload(&wr[idx]), xv);
        az += dot4(ntload(&wz[idx]), xv);
        an += dot4(ntload(&wn[idx]), xv);
    }
    ar = wave_sum(ar); az = wave_sum(az); an = wave_sum(an);
    if (lane == 0) {
        float ir = ar + b_ih[k], iz = az + b_ih[k + H], inn = an + b_ih[k + 2 * H];
        float hr = ws[WS_GH + k], hz = ws[WS_GH + k + H], hn = ws[WS_GH + k + 2 * H];
        float r = 1.f / (1.f + expf(-(ir + hr)));
        float z = 1.f / (1.f + expf(-(iz + hz)));
        float n = tanhf(inn + r * hn);
        h_out[k] = (1.f - z) * n + z * hidden[k];
    }
}

// ============ kDE: persistent logits GEMV + fused log-softmax ============
// 786 co-resident blocks (4 waves each). Wave = online (m,s) over its 4-row groups.
// Arrive via device-scope atomic; last block reduces partials, publishes LSE;
// all blocks then subtract LSE from the rows they themselves wrote.
__global__ __launch_bounds__(256, 4)
void kDE(const float* __restrict__ W_out, const float* __restrict__ b_out,
         const float* __restrict__ h_new, float* __restrict__ logits,
         float* __restrict__ ws)
{
    __shared__ float s_m[4], s_s[4];
    __shared__ float s_off;
    __shared__ int s_last;
    const int tid = threadIdx.x;
    const int wv = tid >> 6, lane = tid & 63;
    const int gw = blockIdx.x * 4 + wv;
    int* wsi = (int*)ws;

    const f4v* h4 = reinterpret_cast<const f4v*>(h_new);
    f4v hv[8];
    #pragma unroll
    for (int t = 0; t < 8; ++t) hv[t] = h4[t * 64 + lane];

    float m_w = -INFINITY, s_w = 0.f;
    for (int g = gw; g < NGRP; g += NW_DE) {
        const int r0 = g * 4;
        const bool u1 = r0 + 1 < V, u2 = r0 + 2 < V, u3 = r0 + 3 < V;
        const f4v* w0 = reinterpret_cast<const f4v*>(W_out + (size_t)r0 * H);
        const f4v* w1 = reinterpret_cast<const f4v*>(W_out + (size_t)(u1 ? r0 + 1 : 0) * H);
        const f4v* w2 = reinterpret_cast<const f4v*>(W_out + (size_t)(u2 ? r0 + 2 : 0) * H);
        const f4v* w3 = reinterpret_cast<const f4v*>(W_out + (size_t)(u3 ? r0 + 3 : 0) * H);
        float a0 = 0.f, a1 = 0.f, a2 = 0.f, a3 = 0.f;
        #pragma unroll
        for (int t = 0; t < 8; ++t) {
            int idx = t * 64 + lane;
            a0 += dot4(ntload(&w0[idx]), hv[t]);
            a1 += dot4(ntload(&w1[idx]), hv[t]);
            a2 += dot4(ntload(&w2[idx]), hv[t]);
            a3 += dot4(ntload(&w3[idx]), hv[t]);
        }
        #pragma unroll
        for (int off = 32; off; off >>= 1) {
            a0 += __shfl_xor(a0, off); a1 += __shfl_xor(a1, off);
            a2 += __shfl_xor(a2, off); a3 += __shfl_xor(a3, off);
        }
        if (lane == 0) {
            const float l0 = a0 + b_out[r0];
            const float l1 = u1 ? a1 + b_out[r0 + 1] : -INFINITY;
            const float l2 = u2 ? a2 + b_out[r0 + 2] : -INFINITY;
            const float l3 = u3 ? a3 + b_out[r0 + 3] : -INFINITY;
            logits[r0] = l0;
            if (u1) logits[r0 + 1] = l1;
            if (u2) logits[r0 + 2] = l2;
            if (u3) logits[r0 + 3] = l3;
            float gm = fmaxf(fmaxf(l0, l1), fmaxf(l2, l3));   // finite (r0 < V always)
            float gs = expf(l0 - gm) + expf(l1 - gm) + expf(l2 - gm) + expf(l3 - gm);
            if (gm > m_w) { s_w = s_w * expf(m_w - gm) + gs; m_w = gm; }
            else          { s_w += gs * expf(gm - m_w); }
        }
    }
    if (lane == 0) { s_m[wv] = m_w; s_s[wv] = s_w; }
    __syncthreads();
    if (tid == 0) {
        float M = fmaxf(fmaxf(s_m[0], s_m[1]), fmaxf(s_m[2], s_m[3]));
        float S = 0.f;
        #pragma unroll
        for (int w = 0; w < 4; ++w) S += s_s[w] * expf(s_m[w] - M);
        ws[WS_PM + blockIdx.x] = M;
        ws[WS_PS + blockIdx.x] = S;
        __threadfence();
        int old = atomicAdd(&wsi[0], 1);
        s_last = (old == NBLK_DE - 1);
    }
    __syncthreads();

    if (s_last) {
        // reduce 786 block partials (L2-hot)
        float m = -INFINITY, s = 0.f;
        for (int i = tid; i < NBLK_DE; i += 256) {
            float mi = ws[WS_PM + i], si = ws[WS_PS + i];
            if (mi > m) { s = s * expf(m - mi) + si; m = mi; }
            else        { s += si * expf(mi - m); }
        }
        #pragma unroll
        for (int off = 32; off; off >>= 1) {
            float m2 = __shfl_xor(m, off), s2 = __shfl_xor(s, off);
            float M = fmaxf(m, m2);
            s = s * expf(m - M) + s2 * expf(m2 - M);
            m = M;
        }
        __syncthreads();   // s_m/s_s reuse
        if (lane == 0) { s_m[wv] = m; s_s[wv] = s; }
        __syncthreads();
        if (tid == 0) {
            float M = fmaxf(fmaxf(s_m[0], s_m[1]), fmaxf(s_m[2], s_m[3]));
            float S = 0.f;
            #pragma unroll
            for (int w = 0; w < 4; ++w) S += s_s[w] * expf(s_m[w] - M);
            float off = M + logf(S);
            __hip_atomic_store(&wsi[2], __float_as_int(off), __ATOMIC_RELAXED, __HIP_MEMORY_SCOPE_AGENT);
            __hip_atomic_store(&wsi[1], 1, __ATOMIC_RELEASE, __HIP_MEMORY_SCOPE_AGENT);
            s_off = off;
        }
    } else {
        if (tid == 0) {
            while (__hip_atomic_load(&wsi[1], __ATOMIC_ACQUIRE, __HIP_MEMORY_SCOPE_AGENT) == 0)
                __builtin_amdgcn_s_sleep(8);
            s_off = __int_as_float(__hip_atomic_load(&wsi[2], __ATOMIC_RELAXED, __HIP_MEMORY_SCOPE_AGENT));
        }
    }
    __syncthreads();
    const float off = s_off;

    // subtract LSE from exactly the rows this wave wrote (block-local data)
    for (int g = gw; g < NGRP; g += NW_DE) {
        const int r = g * 4 + lane;
        if (lane < 4 && r < V) logits[r] -= off;
    }
}

extern "C" void kernel_launch(void* const* d_in, const int* in_sizes, int n_in,
                              void* d_out, int out_size, void* d_ws, size_t ws_size,
                              hipStream_t stream)
{
    const int*   tok      = (const int*)d_in[0];     // int64, read low word
    const float* hidden   = (const float*)d_in[1];   // [1,1,H]
    // d_in[2] = encoder_output: unused by reference
    const float* enc_outs = (const float*)d_in[3];   // [ML,H]
    const float* emb      = (const float*)d_in[4];   // [V,H]
    const float* W_attn   = (const float*)d_in[5];   // [ML,2H]
    const float* b_attn   = (const float*)d_in[6];
    const float* W_comb   = (const float*)d_in[7];   // [H,2H]
    const float* b_comb   = (const float*)d_in[8];
    const float* W_ih     = (const float*)d_in[9];   // [3H,H]
    const float* W_hh     = (const float*)d_in[10];  // [3H,H]
    const float* b_ih     = (const float*)d_in[11];
    const float* b_hh     = (const float*)d_in[12];
    const float* W_out    = (const float*)d_in[13];  // [V,H]
    const float* b_out    = (const float*)d_in[14];

    float* out    = (float*)d_out;
    float* ws     = (float*)d_ws;
    float* logits = out;            // [0, V)
    float* h_out  = out + V;        // [V, V+H)
    float* attnw  = out + V + H;    // [V+H, V+H+ML)

    kA <<<1 + (3 * H) / 16, 1024, 0, stream>>>(tok, hidden, enc_outs, emb,
                                               W_attn, b_attn, W_hh, b_hh, ws, attnw);
    kB <<<H / 4,             256, 0, stream>>>(W_comb, b_comb, ws);
    kC <<<H / 4,             256, 0, stream>>>(W_ih, b_ih, hidden, ws, h_out);
    kDE<<<NBLK_DE,           256, 0, stream>>>(W_out, b_out, h_out, logits, ws);
}

// Round 7
// 137.272 us; speedup vs baseline: 1.9030x; 1.9030x over previous
//
#include <hip/hip_runtime.h>
#include <math.h>

#define H 2048
#define V 50257
#define ML 25

#define NBD ((V + 31) / 32)     // 1571 blocks in kD, 32 rows/block (8 rows/wave)
#define NPART NBD

// ws layout (floats)
#define WS_EMB 16                // embedded [H]
#define WS_ATT (WS_EMB + H)      // attn_applied [H] (contiguous -> cat[2H])
#define WS_X   (WS_EMB + 2 * H)  // relu(combine) [H]
#define WS_GH  (WS_X + H)        // gh = W_hh@h + b_hh [3H]
#define WS_PM  (WS_GH + 3 * H)   // per-block max partials [NPART]
#define WS_PS  (WS_PM + 2048)    // per-block sumexp partials [NPART]

typedef float f4v __attribute__((ext_vector_type(4)));

__device__ __forceinline__ f4v ntload(const f4v* p) { return __builtin_nontemporal_load(p); }
__device__ __forceinline__ float dot4(f4v a, f4v b) {
    return a[0] * b[0] + a[1] * b[1] + a[2] * b[2] + a[3] * b[3];
}
__device__ __forceinline__ float wave_sum(float x) {
    #pragma unroll
    for (int off = 32; off; off >>= 1) x += __shfl_xor(x, off);
    return x;
}

// ============ kA: block 0 = embedding+attention; blocks 1..384 = gh = W_hh@h + b_hh ============
__global__ __launch_bounds__(1024)
void kA(const int* __restrict__ tok_p, const float* __restrict__ hidden,
        const float* __restrict__ enc_outs, const float* __restrict__ emb,
        const float* __restrict__ W_attn, const float* __restrict__ b_attn,
        const float* __restrict__ W_hh, const float* __restrict__ b_hh,
        float* __restrict__ ws, float* __restrict__ attnw)
{
    const int tid = threadIdx.x, bid = blockIdx.x;
    const int wv = tid >> 6, lane = tid & 63;

    if (bid == 0) {
        __shared__ __align__(16) float s_cat[2 * H];
        __shared__ float s_aw[ML];
        const int tok = tok_p[0];   // int64 input, low word (LE)
        const float* erow = emb + (size_t)tok * H;
        for (int h = tid; h < H; h += 1024) {
            float e = erow[h];
            s_cat[h] = e; ws[WS_EMB + h] = e;
            s_cat[H + h] = hidden[h];
        }
        __syncthreads();
        const f4v* c4 = reinterpret_cast<const f4v*>(s_cat);
        for (int l = wv; l < ML; l += 16) {
            const f4v* w4 = reinterpret_cast<const f4v*>(W_attn + (size_t)l * (2 * H));
            float acc = 0.f;
            #pragma unroll
            for (int t = 0; t < 16; ++t) {
                int idx = t * 64 + lane;
                acc += dot4(w4[idx], c4[idx]);
            }
            acc = wave_sum(acc);
            if (lane == 0) s_aw[l] = acc + b_attn[l];
        }
        __syncthreads();
        if (tid == 0) {
            float m = s_aw[0];
            for (int l = 1; l < ML; ++l) m = fmaxf(m, s_aw[l]);
            float s = 0.f;
            for (int l = 0; l < ML; ++l) { float e = expf(s_aw[l] - m); s_aw[l] = e; s += e; }
            float inv = 1.f / s;
            for (int l = 0; l < ML; ++l) { float w = s_aw[l] * inv; s_aw[l] = w; attnw[l] = w; }
        }
        __syncthreads();
        for (int h = tid; h < H; h += 1024) {
            float acc = 0.f;
            #pragma unroll
            for (int l = 0; l < ML; ++l) acc += s_aw[l] * enc_outs[(size_t)l * H + h];
            ws[WS_ATT + h] = acc;
        }
    } else {
        const int r = (bid - 1) * 16 + wv;   // 6144 rows over 384 blocks
        if (r < 3 * H) {
            const f4v* w4 = reinterpret_cast<const f4v*>(W_hh + (size_t)r * H);
            const f4v* h4 = reinterpret_cast<const f4v*>(hidden);
            float acc = 0.f;
            #pragma unroll
            for (int t = 0; t < 8; ++t) {
                int idx = t * 64 + lane;
                acc += dot4(ntload(&w4[idx]), h4[idx]);
            }
            acc = wave_sum(acc);
            if (lane == 0) ws[WS_GH + r] = acc + b_hh[r];
        }
    }
}

// ============ kB: x = relu(W_comb @ cat + b_comb) ============
__global__ __launch_bounds__(256)
void kB(const float* __restrict__ W_comb, const float* __restrict__ b_comb,
        float* __restrict__ ws)
{
    const int tid = threadIdx.x;
    const int wv = tid >> 6, lane = tid & 63;
    const int k = blockIdx.x * 4 + wv;
    const f4v* w4 = reinterpret_cast<const f4v*>(W_comb + (size_t)k * (2 * H));
    const f4v* c4 = reinterpret_cast<const f4v*>(ws + WS_EMB);
    float acc = 0.f;
    #pragma unroll
    for (int t = 0; t < 16; ++t) {
        int idx = t * 64 + lane;
        acc += dot4(ntload(&w4[idx]), c4[idx]);
    }
    acc = wave_sum(acc);
    if (lane == 0) ws[WS_X + k] = fmaxf(acc + b_comb[k], 0.f);
}

// ============ kC: gi = W_ih @ x; gates; h_new ============
__global__ __launch_bounds__(256)
void kC(const float* __restrict__ W_ih, const float* __restrict__ b_ih,
        const float* __restrict__ hidden, const float* __restrict__ ws,
        float* __restrict__ h_out)
{
    const int tid = threadIdx.x;
    const int wv = tid >> 6, lane = tid & 63;
    const int k = blockIdx.x * 4 + wv;
    const f4v* x4 = reinterpret_cast<const f4v*>(ws + WS_X);
    const f4v* wr = reinterpret_cast<const f4v*>(W_ih + (size_t)k * H);
    const f4v* wz = reinterpret_cast<const f4v*>(W_ih + (size_t)(k + H) * H);
    const f4v* wn = reinterpret_cast<const f4v*>(W_ih + (size_t)(k + 2 * H) * H);
    float ar = 0.f, az = 0.f, an = 0.f;
    #pragma unroll
    for (int t = 0; t < 8; ++t) {
        int idx = t * 64 + lane;
        f4v xv = x4[idx];
        ar += dot4(ntload(&wr[idx]), xv);
        az += dot4(ntload(&wz[idx]), xv);
        an += dot4(ntload(&wn[idx]), xv);
    }
    ar = wave_sum(ar); az = wave_sum(az); an = wave_sum(an);
    if (lane == 0) {
        float ir = ar + b_ih[k], iz = az + b_ih[k + H], inn = an + b_ih[k + 2 * H];
        float hr = ws[WS_GH + k], hz = ws[WS_GH + k + H], hn = ws[WS_GH + k + 2 * H];
        float r = 1.f / (1.f + expf(-(ir + hr)));
        float z = 1.f / (1.f + expf(-(iz + hz)));
        float n = tanhf(inn + r * hn);
        h_out[k] = (1.f - z) * n + z * hidden[k];
    }
}

// ============ kD: logits GEMV (8 rows/wave, 32 rows/block) + block partials ============
__global__ __launch_bounds__(256)
void kD(const float* __restrict__ W_out, const float* __restrict__ b_out,
        const float* __restrict__ h_new, float* __restrict__ logits,
        float* __restrict__ ws)
{
    __shared__ float s_m[4], s_s[4];
    const int tid = threadIdx.x;
    const int wv = tid >> 6, lane = tid & 63;
    const int rbase = blockIdx.x * 32 + wv * 8;

    const f4v* h4 = reinterpret_cast<const f4v*>(h_new);
    f4v hv[8];
    #pragma unroll
    for (int t = 0; t < 8; ++t) hv[t] = h4[t * 64 + lane];

    const f4v* wp[8];
    float acc[8];
    #pragma unroll
    for (int r = 0; r < 8; ++r) {
        int rr = rbase + r;
        wp[r] = reinterpret_cast<const f4v*>(W_out + (size_t)(rr < V ? rr : 0) * H);
        acc[r] = 0.f;
    }
    #pragma unroll
    for (int t = 0; t < 8; ++t) {
        int idx = t * 64 + lane;
        #pragma unroll
        for (int r = 0; r < 8; ++r)
            acc[r] += dot4(ntload(&wp[r][idx]), hv[t]);
    }
    #pragma unroll
    for (int r = 0; r < 8; ++r) {
        #pragma unroll
        for (int off = 32; off; off >>= 1) acc[r] += __shfl_xor(acc[r], off);
    }
    if (lane == 0) {
        float m = -INFINITY, s = 0.f;
        #pragma unroll
        for (int r = 0; r < 8; ++r) {
            int rr = rbase + r;
            if (rr < V) {
                float l = acc[r] + b_out[rr];
                logits[rr] = l;
                if (l > m) { s = s * expf(m - l) + 1.f; m = l; }
                else       { s += expf(l - m); }
            }
        }
        s_m[wv] = m; s_s[wv] = s;
    }
    __syncthreads();
    if (tid == 0) {
        float M = fmaxf(fmaxf(s_m[0], s_m[1]), fmaxf(s_m[2], s_m[3]));
        float S = 0.f;
        #pragma unroll
        for (int w = 0; w < 4; ++w) S += s_s[w] * expf(s_m[w] - M);  // 0*exp(-inf)=0
        ws[WS_PM + blockIdx.x] = M;
        ws[WS_PS + blockIdx.x] = S;
    }
}

// ============ kE: every block reduces partials -> (M, LSE), applies its logits stripe ============
__global__ __launch_bounds__(256)
void kE(float* __restrict__ logits, const float* __restrict__ ws)
{
    __shared__ float s_m[4], s_s[4], s_off[1];
    const int tid = threadIdx.x;
    const int wv = tid >> 6, lane = tid & 63;
    const float* pm = ws + WS_PM;
    const float* ps = ws + WS_PS;

    float m = -INFINITY, s = 0.f;
    for (int i = tid; i < NPART; i += 256) {
        float mi = pm[i], si = ps[i];
        if (mi > m) { s = s * expf(m - mi) + si; m = mi; }
        else        { s += si * expf(mi - m); }
    }
    #pragma unroll
    for (int off = 32; off; off >>= 1) {
        float m2 = __shfl_xor(m, off), s2 = __shfl_xor(s, off);
        float M = fmaxf(m, m2);
        s = s * expf(m - M) + s2 * expf(m2 - M);
        m = M;
    }
    if (lane == 0) { s_m[wv] = m; s_s[wv] = s; }
    __syncthreads();
    if (tid == 0) {
        float M = fmaxf(fmaxf(s_m[0], s_m[1]), fmaxf(s_m[2], s_m[3]));
        float S = 0.f;
        #pragma unroll
        for (int w = 0; w < 4; ++w) S += s_s[w] * expf(s_m[w] - M);
        s_off[0] = M + logf(S);
    }
    __syncthreads();
    const float off = s_off[0];
    for (int v = blockIdx.x * 256 + tid; v < V; v += 128 * 256)
        logits[v] -= off;
}

extern "C" void kernel_launch(void* const* d_in, const int* in_sizes, int n_in,
                              void* d_out, int out_size, void* d_ws, size_t ws_size,
                              hipStream_t stream)
{
    const int*   tok      = (const int*)d_in[0];     // int64, read low word
    const float* hidden   = (const float*)d_in[1];   // [1,1,H]
    // d_in[2] = encoder_output: unused by reference
    const float* enc_outs = (const float*)d_in[3];   // [ML,H]
    const float* emb      = (const float*)d_in[4];   // [V,H]
    const float* W_attn   = (const float*)d_in[5];   // [ML,2H]
    const float* b_attn   = (const float*)d_in[6];
    const float* W_comb   = (const float*)d_in[7];   // [H,2H]
    const float* b_comb   = (const float*)d_in[8];
    const float* W_ih     = (const float*)d_in[9];   // [3H,H]
    const float* W_hh     = (const float*)d_in[10];  // [3H,H]
    const float* b_ih     = (const float*)d_in[11];
    const float* b_hh     = (const float*)d_in[12];
    const float* W_out    = (const float*)d_in[13];  // [V,H]
    const float* b_out    = (const float*)d_in[14];

    float* out    = (float*)d_out;
    float* ws     = (float*)d_ws;
    float* logits = out;            // [0, V)
    float* h_out  = out + V;        // [V, V+H)
    float* attnw  = out + V + H;    // [V+H, V+H+ML)

    kA<<<1 + (3 * H) / 16, 1024, 0, stream>>>(tok, hidden, enc_outs, emb,
                                              W_attn, b_attn, W_hh, b_hh, ws, attnw);
    kB<<<H / 4,             256, 0, stream>>>(W_comb, b_comb, ws);
    kC<<<H / 4,             256, 0, stream>>>(W_ih, b_ih, hidden, ws, h_out);
    kD<<<NBD,               256, 0, stream>>>(W_out, b_out, h_out, logits, ws);
    kE<<<128,               256, 0, stream>>>(logits, ws);
}

// Round 8
// 127.396 us; speedup vs baseline: 2.0505x; 1.0775x over previous
//
#include <hip/hip_runtime.h>
#include <math.h>

#define H 2048
#define V 50257
#define ML 25

#define NBD ((V + 15) / 16)     // 3142 blocks in kD, 16 rows/block (4 rows/wave)
#define NPART NBD

// ws layout (floats)
#define WS_EMB 16                // embedded [H]
#define WS_ATT (WS_EMB + H)      // attn_applied [H] (contiguous -> cat[2H])
#define WS_X   (WS_EMB + 2 * H)  // relu(combine) [H]
#define WS_GH  (WS_X + H)        // gh = W_hh@h + b_hh [3H]
#define WS_PM  (WS_GH + 3 * H)   // per-block max partials [NPART]
#define WS_PS  (WS_PM + 3200)    // per-block sumexp partials [NPART]

typedef float f4v __attribute__((ext_vector_type(4)));

__device__ __forceinline__ f4v ntload(const f4v* p) { return __builtin_nontemporal_load(p); }
__device__ __forceinline__ float dot4(f4v a, f4v b) {
    return a[0] * b[0] + a[1] * b[1] + a[2] * b[2] + a[3] * b[3];
}
__device__ __forceinline__ float wave_sum(float x) {
    #pragma unroll
    for (int off = 32; off; off >>= 1) x += __shfl_xor(x, off);
    return x;
}

// ============ kA: block 0 = embedding+attention; blocks 1..384 = gh = W_hh@h + b_hh ============
__global__ __launch_bounds__(1024)
void kA(const int* __restrict__ tok_p, const float* __restrict__ hidden,
        const float* __restrict__ enc_outs, const float* __restrict__ emb,
        const float* __restrict__ W_attn, const float* __restrict__ b_attn,
        const float* __restrict__ W_hh, const float* __restrict__ b_hh,
        float* __restrict__ ws, float* __restrict__ attnw)
{
    const int tid = threadIdx.x, bid = blockIdx.x;
    const int wv = tid >> 6, lane = tid & 63;

    if (bid == 0) {
        __shared__ __align__(16) float s_cat[2 * H];
        __shared__ float s_aw[ML];
        const int tok = tok_p[0];   // int64 input, low word (LE)
        const float* erow = emb + (size_t)tok * H;
        for (int h = tid; h < H; h += 1024) {
            float e = erow[h];
            s_cat[h] = e; ws[WS_EMB + h] = e;
            s_cat[H + h] = hidden[h];
        }
        __syncthreads();
        const f4v* c4 = reinterpret_cast<const f4v*>(s_cat);
        for (int l = wv; l < ML; l += 16) {
            const f4v* w4 = reinterpret_cast<const f4v*>(W_attn + (size_t)l * (2 * H));
            float acc = 0.f;
            #pragma unroll
            for (int t = 0; t < 16; ++t) {
                int idx = t * 64 + lane;
                acc += dot4(w4[idx], c4[idx]);
            }
            acc = wave_sum(acc);
            if (lane == 0) s_aw[l] = acc + b_attn[l];
        }
        __syncthreads();
        if (tid == 0) {
            float m = s_aw[0];
            for (int l = 1; l < ML; ++l) m = fmaxf(m, s_aw[l]);
            float s = 0.f;
            for (int l = 0; l < ML; ++l) { float e = expf(s_aw[l] - m); s_aw[l] = e; s += e; }
            float inv = 1.f / s;
            for (int l = 0; l < ML; ++l) { float w = s_aw[l] * inv; s_aw[l] = w; attnw[l] = w; }
        }
        __syncthreads();
        for (int h = tid; h < H; h += 1024) {
            float acc = 0.f;
            #pragma unroll
            for (int l = 0; l < ML; ++l) acc += s_aw[l] * enc_outs[(size_t)l * H + h];
            ws[WS_ATT + h] = acc;
        }
    } else {
        const int r = (bid - 1) * 16 + wv;   // 6144 rows over 384 blocks
        if (r < 3 * H) {
            const f4v* w4 = reinterpret_cast<const f4v*>(W_hh + (size_t)r * H);
            const f4v* h4 = reinterpret_cast<const f4v*>(hidden);
            float acc = 0.f;
            #pragma unroll
            for (int t = 0; t < 8; ++t) {
                int idx = t * 64 + lane;
                acc += dot4(ntload(&w4[idx]), h4[idx]);
            }
            acc = wave_sum(acc);
            if (lane == 0) ws[WS_GH + r] = acc + b_hh[r];
        }
    }
}

// ============ kB: x = relu(W_comb @ cat + b_comb) ============
__global__ __launch_bounds__(256)
void kB(const float* __restrict__ W_comb, const float* __restrict__ b_comb,
        float* __restrict__ ws)
{
    const int tid = threadIdx.x;
    const int wv = tid >> 6, lane = tid & 63;
    const int k = blockIdx.x * 4 + wv;
    const f4v* w4 = reinterpret_cast<const f4v*>(W_comb + (size_t)k * (2 * H));
    const f4v* c4 = reinterpret_cast<const f4v*>(ws + WS_EMB);
    float acc = 0.f;
    #pragma unroll
    for (int t = 0; t < 16; ++t) {
        int idx = t * 64 + lane;
        acc += dot4(ntload(&w4[idx]), c4[idx]);
    }
    acc = wave_sum(acc);
    if (lane == 0) ws[WS_X + k] = fmaxf(acc + b_comb[k], 0.f);
}

// ============ kC: gi = W_ih @ x; gates; h_new ============
__global__ __launch_bounds__(256)
void kC(const float* __restrict__ W_ih, const float* __restrict__ b_ih,
        const float* __restrict__ hidden, const float* __restrict__ ws,
        float* __restrict__ h_out)
{
    const int tid = threadIdx.x;
    const int wv = tid >> 6, lane = tid & 63;
    const int k = blockIdx.x * 4 + wv;
    const f4v* x4 = reinterpret_cast<const f4v*>(ws + WS_X);
    const f4v* wr = reinterpret_cast<const f4v*>(W_ih + (size_t)k * H);
    const f4v* wz = reinterpret_cast<const f4v*>(W_ih + (size_t)(k + H) * H);
    const f4v* wn = reinterpret_cast<const f4v*>(W_ih + (size_t)(k + 2 * H) * H);
    float ar = 0.f, az = 0.f, an = 0.f;
    #pragma unroll
    for (int t = 0; t < 8; ++t) {
        int idx = t * 64 + lane;
        f4v xv = x4[idx];
        ar += dot4(ntload(&wr[idx]), xv);
        az += dot4(ntload(&wz[idx]), xv);
        an += dot4(ntload(&wn[idx]), xv);
    }
    ar = wave_sum(ar); az = wave_sum(az); an = wave_sum(an);
    if (lane == 0) {
        float ir = ar + b_ih[k], iz = az + b_ih[k + H], inn = an + b_ih[k + 2 * H];
        float hr = ws[WS_GH + k], hz = ws[WS_GH + k + H], hn = ws[WS_GH + k + 2 * H];
        float r = 1.f / (1.f + expf(-(ir + hr)));
        float z = 1.f / (1.f + expf(-(iz + hz)));
        float n = tanhf(inn + r * hn);
        h_out[k] = (1.f - z) * n + z * hidden[k];
    }
}

// ============ kD: logits GEMV (4 rows/wave, 16 rows/block) + block partials ============
// A/B vs round 5: plain (cached) loads instead of nontemporal on the W_out stream.
__global__ __launch_bounds__(256)
void kD(const float* __restrict__ W_out, const float* __restrict__ b_out,
        const float* __restrict__ h_new, float* __restrict__ logits,
        float* __restrict__ ws)
{
    __shared__ float s_m[4], s_s[4];
    const int tid = threadIdx.x;
    const int wv = tid >> 6, lane = tid & 63;
    const int rbase = blockIdx.x * 16 + wv * 4;

    const f4v* h4 = reinterpret_cast<const f4v*>(h_new);
    f4v hv[8];
    #pragma unroll
    for (int t = 0; t < 8; ++t) hv[t] = h4[t * 64 + lane];

    const int  r0 = rbase, r1 = rbase + 1, r2 = rbase + 2, r3 = rbase + 3;
    const bool v0 = r0 < V, v1 = r1 < V, v2 = r2 < V, v3 = r3 < V;
    const f4v* w0 = reinterpret_cast<const f4v*>(W_out + (size_t)(v0 ? r0 : 0) * H);
    const f4v* w1 = reinterpret_cast<const f4v*>(W_out + (size_t)(v1 ? r1 : 0) * H);
    const f4v* w2 = reinterpret_cast<const f4v*>(W_out + (size_t)(v2 ? r2 : 0) * H);
    const f4v* w3 = reinterpret_cast<const f4v*>(W_out + (size_t)(v3 ? r3 : 0) * H);

    float a0 = 0.f, a1 = 0.f, a2 = 0.f, a3 = 0.f;
    #pragma unroll
    for (int t = 0; t < 8; ++t) {
        int idx = t * 64 + lane;
        a0 += dot4(w0[idx], hv[t]);
        a1 += dot4(w1[idx], hv[t]);
        a2 += dot4(w2[idx], hv[t]);
        a3 += dot4(w3[idx], hv[t]);
    }
    #pragma unroll
    for (int off = 32; off; off >>= 1) {
        a0 += __shfl_xor(a0, off); a1 += __shfl_xor(a1, off);
        a2 += __shfl_xor(a2, off); a3 += __shfl_xor(a3, off);
    }
    const float l0 = v0 ? a0 + b_out[r0] : -INFINITY;
    const float l1 = v1 ? a1 + b_out[r1] : -INFINITY;
    const float l2 = v2 ? a2 + b_out[r2] : -INFINITY;
    const float l3 = v3 ? a3 + b_out[r3] : -INFINITY;
    if (lane == 0) {
        if (v0) logits[r0] = l0;
        if (v1) logits[r1] = l1;
        if (v2) logits[r2] = l2;
        if (v3) logits[r3] = l3;
        float m = fmaxf(fmaxf(l0, l1), fmaxf(l2, l3));
        float s = 0.f;
        if (m > -INFINITY)
            s = expf(l0 - m) + expf(l1 - m) + expf(l2 - m) + expf(l3 - m);
        s_m[wv] = m; s_s[wv] = s;
    }
    __syncthreads();
    if (tid == 0) {
        float M = fmaxf(fmaxf(s_m[0], s_m[1]), fmaxf(s_m[2], s_m[3]));
        float S = 0.f;
        #pragma unroll
        for (int w = 0; w < 4; ++w) S += s_s[w] * expf(s_m[w] - M);  // 0*exp(-inf)=0
        ws[WS_PM + blockIdx.x] = M;
        ws[WS_PS + blockIdx.x] = S;
    }
}

// ============ kE: every block reduces partials -> (M, LSE), applies its logits stripe ============
__global__ __launch_bounds__(256)
void kE(float* __restrict__ logits, const float* __restrict__ ws)
{
    __shared__ float s_m[4], s_s[4], s_off[1];
    const int tid = threadIdx.x;
    const int wv = tid >> 6, lane = tid & 63;
    const float* pm = ws + WS_PM;
    const float* ps = ws + WS_PS;

    float m = -INFINITY, s = 0.f;
    for (int i = tid; i < NPART; i += 256) {
        float mi = pm[i], si = ps[i];
        if (mi > m) { s = s * expf(m - mi) + si; m = mi; }
        else        { s += si * expf(mi - m); }
    }
    #pragma unroll
    for (int off = 32; off; off >>= 1) {
        float m2 = __shfl_xor(m, off), s2 = __shfl_xor(s, off);
        float M = fmaxf(m, m2);
        s = s * expf(m - M) + s2 * expf(m2 - M);
        m = M;
    }
    if (lane == 0) { s_m[wv] = m; s_s[wv] = s; }
    __syncthreads();
    if (tid == 0) {
        float M = fmaxf(fmaxf(s_m[0], s_m[1]), fmaxf(s_m[2], s_m[3]));
        float S = 0.f;
        #pragma unroll
        for (int w = 0; w < 4; ++w) S += s_s[w] * expf(s_m[w] - M);
        s_off[0] = M + logf(S);
    }
    __syncthreads();
    const float off = s_off[0];
    for (int v = blockIdx.x * 256 + tid; v < V; v += 128 * 256)
        logits[v] -= off;
}

extern "C" void kernel_launch(void* const* d_in, const int* in_sizes, int n_in,
                              void* d_out, int out_size, void* d_ws, size_t ws_size,
                              hipStream_t stream)
{
    const int*   tok      = (const int*)d_in[0];     // int64, read low word
    const float* hidden   = (const float*)d_in[1];   // [1,1,H]
    // d_in[2] = encoder_output: unused by reference
    const float* enc_outs = (const float*)d_in[3];   // [ML,H]
    const float* emb      = (const float*)d_in[4];   // [V,H]
    const float* W_attn   = (const float*)d_in[5];   // [ML,2H]
    const float* b_attn   = (const float*)d_in[6];
    const float* W_comb   = (const float*)d_in[7];   // [H,2H]
    const float* b_comb   = (const float*)d_in[8];
    const float* W_ih     = (const float*)d_in[9];   // [3H,H]
    const float* W_hh     = (const float*)d_in[10];  // [3H,H]
    const float* b_ih     = (const float*)d_in[11];
    const float* b_hh     = (const float*)d_in[12];
    const float* W_out    = (const float*)d_in[13];  // [V,H]
    const float* b_out    = (const float*)d_in[14];

    float* out    = (float*)d_out;
    float* ws     = (float*)d_ws;
    float* logits = out;            // [0, V)
    float* h_out  = out + V;        // [V, V+H)
    float* attnw  = out + V + H;    // [V+H, V+H+ML)

    kA<<<1 + (3 * H) / 16, 1024, 0, stream>>>(tok, hidden, enc_outs, emb,
                                              W_attn, b_attn, W_hh, b_hh, ws, attnw);
    kB<<<H / 4,             256, 0, stream>>>(W_comb, b_comb, ws);
    kC<<<H / 4,             256, 0, stream>>>(W_ih, b_ih, hidden, ws, h_out);
    kD<<<NBD,               256, 0, stream>>>(W_out, b_out, h_out, logits, ws);
    kE<<<128,               256, 0, stream>>>(logits, ws);
}

// Round 9
// 105.178 us; speedup vs baseline: 2.4837x; 1.2112x over previous
//
#include <hip/hip_runtime.h>
#include <math.h>

#define H 2048
#define V 50257
#define ML 25

#define NBD ((V + 15) / 16)     // 3142 blocks in kD, 16 rows/block (4 rows/wave)
#define NPART NBD

// ws layout (floats)
#define WS_EMB 16                // embedded [H]
#define WS_ATT (WS_EMB + H)      // attn_applied [H] (contiguous -> cat[2H])
#define WS_X   (WS_EMB + 2 * H)  // relu(combine) [H]
#define WS_GH  (WS_X + H)        // gh = W_hh@h + b_hh [3H]
#define WS_PM  (WS_GH + 3 * H)   // per-block max partials [NPART]
#define WS_PS  (WS_PM + 3200)    // per-block sumexp partials [NPART]

typedef float f4v __attribute__((ext_vector_type(4)));

__device__ __forceinline__ f4v ntload(const f4v* p) { return __builtin_nontemporal_load(p); }
__device__ __forceinline__ float dot4(f4v a, f4v b) {
    return a[0] * b[0] + a[1] * b[1] + a[2] * b[2] + a[3] * b[3];
}
__device__ __forceinline__ float wave_sum(float x) {
    #pragma unroll
    for (int off = 32; off; off >>= 1) x += __shfl_xor(x, off);
    return x;
}

// ============ kA: block 0 = embedding+attention; blocks 1..384 = gh = W_hh@h + b_hh ============
__global__ __launch_bounds__(1024)
void kA(const int* __restrict__ tok_p, const float* __restrict__ hidden,
        const float* __restrict__ enc_outs, const float* __restrict__ emb,
        const float* __restrict__ W_attn, const float* __restrict__ b_attn,
        const float* __restrict__ W_hh, const float* __restrict__ b_hh,
        float* __restrict__ ws, float* __restrict__ attnw)
{
    const int tid = threadIdx.x, bid = blockIdx.x;
    const int wv = tid >> 6, lane = tid & 63;

    if (bid == 0) {
        __shared__ __align__(16) float s_cat[2 * H];
        __shared__ float s_aw[ML];
        const int tok = tok_p[0];   // int64 input, low word (LE)
        const float* erow = emb + (size_t)tok * H;
        for (int h = tid; h < H; h += 1024) {
            float e = erow[h];
            s_cat[h] = e; ws[WS_EMB + h] = e;
            s_cat[H + h] = hidden[h];
        }
        __syncthreads();
        const f4v* c4 = reinterpret_cast<const f4v*>(s_cat);
        for (int l = wv; l < ML; l += 16) {
            const f4v* w4 = reinterpret_cast<const f4v*>(W_attn + (size_t)l * (2 * H));
            float acc = 0.f;
            #pragma unroll
            for (int t = 0; t < 16; ++t) {
                int idx = t * 64 + lane;
                acc += dot4(w4[idx], c4[idx]);
            }
            acc = wave_sum(acc);
            if (lane == 0) s_aw[l] = acc + b_attn[l];
        }
        __syncthreads();
        if (tid == 0) {
            float m = s_aw[0];
            for (int l = 1; l < ML; ++l) m = fmaxf(m, s_aw[l]);
            float s = 0.f;
            for (int l = 0; l < ML; ++l) { float e = expf(s_aw[l] - m); s_aw[l] = e; s += e; }
            float inv = 1.f / s;
            for (int l = 0; l < ML; ++l) { float w = s_aw[l] * inv; s_aw[l] = w; attnw[l] = w; }
        }
        __syncthreads();
        for (int h = tid; h < H; h += 1024) {
            float acc = 0.f;
            #pragma unroll
            for (int l = 0; l < ML; ++l) acc += s_aw[l] * enc_outs[(size_t)l * H + h];
            ws[WS_ATT + h] = acc;
        }
    } else {
        const int r = (bid - 1) * 16 + wv;   // 6144 rows over 384 blocks
        if (r < 3 * H) {
            const f4v* w4 = reinterpret_cast<const f4v*>(W_hh + (size_t)r * H);
            const f4v* h4 = reinterpret_cast<const f4v*>(hidden);
            float acc = 0.f;
            #pragma unroll
            for (int t = 0; t < 8; ++t) {
                int idx = t * 64 + lane;
                acc += dot4(ntload(&w4[idx]), h4[idx]);
            }
            acc = wave_sum(acc);
            if (lane == 0) ws[WS_GH + r] = acc + b_hh[r];
        }
    }
}

// ============ kB: x = relu(W_comb @ cat + b_comb) ============
__global__ __launch_bounds__(256)
void kB(const float* __restrict__ W_comb, const float* __restrict__ b_comb,
        float* __restrict__ ws)
{
    const int tid = threadIdx.x;
    const int wv = tid >> 6, lane = tid & 63;
    const int k = blockIdx.x * 4 + wv;
    const f4v* w4 = reinterpret_cast<const f4v*>(W_comb + (size_t)k * (2 * H));
    const f4v* c4 = reinterpret_cast<const f4v*>(ws + WS_EMB);
    float acc = 0.f;
    #pragma unroll
    for (int t = 0; t < 16; ++t) {
        int idx = t * 64 + lane;
        acc += dot4(ntload(&w4[idx]), c4[idx]);
    }
    acc = wave_sum(acc);
    if (lane == 0) ws[WS_X + k] = fmaxf(acc + b_comb[k], 0.f);
}

// ============ kC: gi = W_ih @ x; gates; h_new ============
__global__ __launch_bounds__(256)
void kC(const float* __restrict__ W_ih, const float* __restrict__ b_ih,
        const float* __restrict__ hidden, const float* __restrict__ ws,
        float* __restrict__ h_out)
{
    const int tid = threadIdx.x;
    const int wv = tid >> 6, lane = tid & 63;
    const int k = blockIdx.x * 4 + wv;
    const f4v* x4 = reinterpret_cast<const f4v*>(ws + WS_X);
    const f4v* wr = reinterpret_cast<const f4v*>(W_ih + (size_t)k * H);
    const f4v* wz = reinterpret_cast<const f4v*>(W_ih + (size_t)(k + H) * H);
    const f4v* wn = reinterpret_cast<const f4v*>(W_ih + (size_t)(k + 2 * H) * H);
    float ar = 0.f, az = 0.f, an = 0.f;
    #pragma unroll
    for (int t = 0; t < 8; ++t) {
        int idx = t * 64 + lane;
        f4v xv = x4[idx];
        ar += dot4(ntload(&wr[idx]), xv);
        az += dot4(ntload(&wz[idx]), xv);
        an += dot4(ntload(&wn[idx]), xv);
    }
    ar = wave_sum(ar); az = wave_sum(az); an = wave_sum(an);
    if (lane == 0) {
        float ir = ar + b_ih[k], iz = az + b_ih[k + H], inn = an + b_ih[k + 2 * H];
        float hr = ws[WS_GH + k], hz = ws[WS_GH + k + H], hn = ws[WS_GH + k + 2 * H];
        float r = 1.f / (1.f + expf(-(ir + hr)));
        float z = 1.f / (1.f + expf(-(iz + hz)));
        float n = tanhf(inn + r * hn);
        h_out[k] = (1.f - z) * n + z * hidden[k];
    }
}

// ============ kD: logits GEMV (4 rows/wave, 16 rows/block) + block partials ============
__global__ __launch_bounds__(256)
void kD(const float* __restrict__ W_out, const float* __restrict__ b_out,
        const float* __restrict__ h_new, float* __restrict__ logits,
        float* __restrict__ ws)
{
    __shared__ float s_m[4], s_s[4];
    const int tid = threadIdx.x;
    const int wv = tid >> 6, lane = tid & 63;
    const int rbase = blockIdx.x * 16 + wv * 4;

    const f4v* h4 = reinterpret_cast<const f4v*>(h_new);
    f4v hv[8];
    #pragma unroll
    for (int t = 0; t < 8; ++t) hv[t] = h4[t * 64 + lane];

    const int  r0 = rbase, r1 = rbase + 1, r2 = rbase + 2, r3 = rbase + 3;
    const bool v0 = r0 < V, v1 = r1 < V, v2 = r2 < V, v3 = r3 < V;
    const f4v* w0 = reinterpret_cast<const f4v*>(W_out + (size_t)(v0 ? r0 : 0) * H);
    const f4v* w1 = reinterpret_cast<const f4v*>(W_out + (size_t)(v1 ? r1 : 0) * H);
    const f4v* w2 = reinterpret_cast<const f4v*>(W_out + (size_t)(v2 ? r2 : 0) * H);
    const f4v* w3 = reinterpret_cast<const f4v*>(W_out + (size_t)(v3 ? r3 : 0) * H);

    float a0 = 0.f, a1 = 0.f, a2 = 0.f, a3 = 0.f;
    #pragma unroll
    for (int t = 0; t < 8; ++t) {
        int idx = t * 64 + lane;
        a0 += dot4(ntload(&w0[idx]), hv[t]);
        a1 += dot4(ntload(&w1[idx]), hv[t]);
        a2 += dot4(ntload(&w2[idx]), hv[t]);
        a3 += dot4(ntload(&w3[idx]), hv[t]);
    }
    #pragma unroll
    for (int off = 32; off; off >>= 1) {
        a0 += __shfl_xor(a0, off); a1 += __shfl_xor(a1, off);
        a2 += __shfl_xor(a2, off); a3 += __shfl_xor(a3, off);
    }
    const float l0 = v0 ? a0 + b_out[r0] : -INFINITY;
    const float l1 = v1 ? a1 + b_out[r1] : -INFINITY;
    const float l2 = v2 ? a2 + b_out[r2] : -INFINITY;
    const float l3 = v3 ? a3 + b_out[r3] : -INFINITY;
    if (lane == 0) {
        if (v0) logits[r0] = l0;
        if (v1) logits[r1] = l1;
        if (v2) logits[r2] = l2;
        if (v3) logits[r3] = l3;
        float m = fmaxf(fmaxf(l0, l1), fmaxf(l2, l3));
        float s = 0.f;
        if (m > -INFINITY)
            s = expf(l0 - m) + expf(l1 - m) + expf(l2 - m) + expf(l3 - m);
        s_m[wv] = m; s_s[wv] = s;
    }
    __syncthreads();
    if (tid == 0) {
        float M = fmaxf(fmaxf(s_m[0], s_m[1]), fmaxf(s_m[2], s_m[3]));
        float S = 0.f;
        #pragma unroll
        for (int w = 0; w < 4; ++w) S += s_s[w] * expf(s_m[w] - M);  // 0*exp(-inf)=0
        ws[WS_PM + blockIdx.x] = M;
        ws[WS_PS + blockIdx.x] = S;
    }
}

// ============ kE: every block reduces partials -> (M, LSE), applies its logits stripe ============
__global__ __launch_bounds__(256)
void kE(float* __restrict__ logits, const float* __restrict__ ws)
{
    __shared__ float s_m[4], s_s[4], s_off[1];
    const int tid = threadIdx.x;
    const int wv = tid >> 6, lane = tid & 63;
    const float* pm = ws + WS_PM;
    const float* ps = ws + WS_PS;

    float m = -INFINITY, s = 0.f;
    for (int i = tid; i < NPART; i += 256) {
        float mi = pm[i], si = ps[i];
        if (mi > m) { s = s * expf(m - mi) + si; m = mi; }
        else        { s += si * expf(mi - m); }
    }
    #pragma unroll
    for (int off = 32; off; off >>= 1) {
        float m2 = __shfl_xor(m, off), s2 = __shfl_xor(s, off);
        float M = fmaxf(m, m2);
        s = s * expf(m - M) + s2 * expf(m2 - M);
        m = M;
    }
    if (lane == 0) { s_m[wv] = m; s_s[wv] = s; }
    __syncthreads();
    if (tid == 0) {
        float M = fmaxf(fmaxf(s_m[0], s_m[1]), fmaxf(s_m[2], s_m[3]));
        float S = 0.f;
        #pragma unroll
        for (int w = 0; w < 4; ++w) S += s_s[w] * expf(s_m[w] - M);
        s_off[0] = M + logf(S);
    }
    __syncthreads();
    const float off = s_off[0];
    for (int v = blockIdx.x * 256 + tid; v < V; v += 128 * 256)
        logits[v] -= off;
}

extern "C" void kernel_launch(void* const* d_in, const int* in_sizes, int n_in,
                              void* d_out, int out_size, void* d_ws, size_t ws_size,
                              hipStream_t stream)
{
    const int*   tok      = (const int*)d_in[0];     // int64, read low word
    const float* hidden   = (const float*)d_in[1];   // [1,1,H]
    // d_in[2] = encoder_output: unused by reference
    const float* enc_outs = (const float*)d_in[3];   // [ML,H]
    const float* emb      = (const float*)d_in[4];   // [V,H]
    const float* W_attn   = (const float*)d_in[5];   // [ML,2H]
    const float* b_attn   = (const float*)d_in[6];
    const float* W_comb   = (const float*)d_in[7];   // [H,2H]
    const float* b_comb   = (const float*)d_in[8];
    const float* W_ih     = (const float*)d_in[9];   // [3H,H]
    const float* W_hh     = (const float*)d_in[10];  // [3H,H]
    const float* b_ih     = (const float*)d_in[11];
    const float* b_hh     = (const float*)d_in[12];
    const float* W_out    = (const float*)d_in[13];  // [V,H]
    const float* b_out    = (const float*)d_in[14];

    float* out    = (float*)d_out;
    float* ws     = (float*)d_ws;
    float* logits = out;            // [0, V)
    float* h_out  = out + V;        // [V, V+H)
    float* attnw  = out + V + H;    // [V+H, V+H+ML)

    kA<<<1 + (3 * H) / 16, 1024, 0, stream>>>(tok, hidden, enc_outs, emb,
                                              W_attn, b_attn, W_hh, b_hh, ws, attnw);
    kB<<<H / 4,             256, 0, stream>>>(W_comb, b_comb, ws);
    kC<<<H / 4,             256, 0, stream>>>(W_ih, b_ih, hidden, ws, h_out);
    kD<<<NBD,               256, 0, stream>>>(W_out, b_out, h_out, logits, ws);
    kE<<<128,               256, 0, stream>>>(logits, ws);
}